// Round 9
// baseline (266.785 us; speedup 1.0000x reference)
//
#include <hip/hip_runtime.h>
#include <hip/hip_bf16.h>

#define S_LEN   2048
#define NHEADS  16
#define DKH     64
#define DMODEL  1024
#define NBATCH  2

typedef __bf16 bf16x8 __attribute__((ext_vector_type(8)));
typedef __bf16 bf16x4 __attribute__((ext_vector_type(4)));
typedef float  f32x4  __attribute__((ext_vector_type(4)));

typedef __attribute__((address_space(3))) void       lds_void;
typedef const __attribute__((address_space(1))) void glob_void;

__device__ __forceinline__ void glds16(const void* g, void* l) {
    __builtin_amdgcn_global_load_lds((glob_void*)g, (lds_void*)l, 16, 0, 0);
}

// ---------------- fp32 -> bf16 pre-convert (weights only, 4 MB) -------------
__global__ __launch_bounds__(256)
void cvt_w_k(const float* __restrict__ wq, const float* __restrict__ wk,
             const float* __restrict__ wv, const float* __restrict__ wo,
             __bf16* __restrict__ dst)
{
    const float* srcs[4] = {wq, wk, wv, wo};
    const float* s = srcs[blockIdx.y];
    __bf16* d = dst + (size_t)blockIdx.y * (DMODEL * DMODEL);
    const size_t i = ((size_t)blockIdx.x * 256 + threadIdx.x) * 8;
    f32x4 lo = *(const f32x4*)(s + i);
    f32x4 hi = *(const f32x4*)(s + i + 4);
    bf16x8 r;
#pragma unroll
    for (int k = 0; k < 4; ++k) { r[k] = (__bf16)lo[k]; r[4 + k] = (__bf16)hi[k]; }
    *(bf16x8*)(d + i) = r;
}

// ---------------- GEMM core: 128x128 tile, BK=32, mixed staging -------------
// AF32: A-operand fp32 (VGPR->cvt->LDS); else bf16 via global_load_lds.
// WF32: W-operand fp32 likewise. 256 thr / 4 waves; wave = 64x64 (16 MFMA/step).
template<bool AF32, bool WF32>
__device__ __forceinline__ void gemm_core(
    const void* __restrict__ Ap, const void* __restrict__ Wp,
    int m0, int n0, int K,
    __bf16 (*As)[32], __bf16 (*Ws)[32], f32x4 acc[4][4])
{
    const int tid  = threadIdx.x;
    const int lane = tid & 63;
    const int wv   = tid >> 6;
    const int l15  = lane & 15;
    const int quad = lane >> 4;
    const int wm   = wv >> 1;
    const int wn   = wv & 1;
    const int grow = lane >> 2;
    const int gcol = (lane & 3) * 8;

    // bf16 glds maps
    const __bf16* ag0 = (const __bf16*)Ap + (size_t)(m0 + wv * 32 + grow) * K + gcol;
    const __bf16* ag1 = (const __bf16*)Ap + (size_t)(m0 + wv * 32 + 16 + grow) * K + gcol;
    const __bf16* wg0 = (const __bf16*)Wp + (size_t)(n0 + wv * 32 + grow) * K + gcol;
    const __bf16* wg1 = (const __bf16*)Wp + (size_t)(n0 + wv * 32 + 16 + grow) * K + gcol;
    void* al0 = &As[wv * 32][0];
    void* al1 = &As[wv * 32 + 16][0];
    void* wl0 = &Ws[wv * 32][0];
    void* wl1 = &Ws[wv * 32 + 16][0];

    // fp32 staging map: 128 rows x 32 k f32, 16 f32/thread
    const int fr = tid >> 1;
    const int fc = (tid & 1) * 16;
    const float* afp = (const float*)Ap + (size_t)(m0 + fr) * K + fc;
    const float* wfp = (const float*)Wp + (size_t)(n0 + fr) * K + fc;

    f32x4 apf[4], wpf[4];
    if (AF32) {
#pragma unroll
        for (int t = 0; t < 4; ++t) apf[t] = *(const f32x4*)(afp + t * 4);
    }
    if (WF32) {
#pragma unroll
        for (int t = 0; t < 4; ++t) wpf[t] = *(const f32x4*)(wfp + t * 4);
    }

    for (int k0 = 0;;) {
        __syncthreads();                   // prior frag reads complete
        if (AF32) {
            bf16x8 v0, v1;
#pragma unroll
            for (int t = 0; t < 4; ++t) {
                v0[t] = (__bf16)apf[0][t]; v0[4 + t] = (__bf16)apf[1][t];
                v1[t] = (__bf16)apf[2][t]; v1[4 + t] = (__bf16)apf[3][t];
            }
            *(bf16x8*)&As[fr][fc]     = v0;
            *(bf16x8*)&As[fr][fc + 8] = v1;
        } else {
            glds16(ag0 + k0, al0);
            glds16(ag1 + k0, al1);
        }
        if (WF32) {
            bf16x8 v0, v1;
#pragma unroll
            for (int t = 0; t < 4; ++t) {
                v0[t] = (__bf16)wpf[0][t]; v0[4 + t] = (__bf16)wpf[1][t];
                v1[t] = (__bf16)wpf[2][t]; v1[4 + t] = (__bf16)wpf[3][t];
            }
            *(bf16x8*)&Ws[fr][fc]     = v0;
            *(bf16x8*)&Ws[fr][fc + 8] = v1;
        } else {
            glds16(wg0 + k0, wl0);
            glds16(wg1 + k0, wl1);
        }
        __syncthreads();                   // tiles visible
        k0 += 32;
        if (k0 < K) {                      // prefetch next fp32 tiles
            if (AF32) {
#pragma unroll
                for (int t = 0; t < 4; ++t) apf[t] = *(const f32x4*)(afp + k0 + t * 4);
            }
            if (WF32) {
#pragma unroll
                for (int t = 0; t < 4; ++t) wpf[t] = *(const f32x4*)(wfp + k0 + t * 4);
            }
        }

        bf16x8 af[4], wf[4];
#pragma unroll
        for (int i = 0; i < 4; ++i)
            af[i] = *(const bf16x8*)&As[wm * 64 + i * 16 + l15][quad * 8];
#pragma unroll
        for (int j = 0; j < 4; ++j)
            wf[j] = *(const bf16x8*)&Ws[wn * 64 + j * 16 + l15][quad * 8];
#pragma unroll
        for (int i = 0; i < 4; ++i)
#pragma unroll
            for (int j = 0; j < 4; ++j)
                acc[i][j] = __builtin_amdgcn_mfma_f32_16x16x32_bf16(af[i], wf[j], acc[i][j], 0, 0, 0);

        if (k0 >= K) break;
    }
}

// ---------------- single-dispatch QKV projections ----------------
// z 0: Q = Qi(fp32)@Wq^T (+bq)*0.125 -> [b,h,s,d]
// z 1: K = Ki(fp32)@Wk^T (+bk)       -> [b,h,s,d]
// z 2: vT = Wv@Vi(fp32)^T (+bv/row)  -> [b,h,d,s] (coalesced)
struct GArgs {
    const void* A[3];
    const void* W[3];
    const float* bias[3];
    __bf16*     out[3];
};

__global__ __launch_bounds__(256)
void gemm_qkv(GArgs g)
{
    __shared__ __align__(16) __bf16 As[128][32];
    __shared__ __align__(16) __bf16 Ws[128][32];

    const int fid = blockIdx.x;
    const int z   = fid >> 8;
    const int l   = fid & 255;
    const int x   = l & 7;               // XCD (heuristic: XCD = blockIdx % 8)
    const int t   = l >> 3;              // 0..31
    int m0, n0;
    if (z == 2) { m0 = (t & 7) * 128;           n0 = (x * 4 + (t >> 3)) * 128; }
    else        { m0 = (x * 4 + (t & 3)) * 128; n0 = (t >> 2) * 128; }

    f32x4 acc[4][4];
#pragma unroll
    for (int i = 0; i < 4; ++i)
#pragma unroll
        for (int j = 0; j < 4; ++j) acc[i][j] = (f32x4){0.f, 0.f, 0.f, 0.f};

    if (z == 2) gemm_core<false, true>(g.A[2], g.W[2], m0, n0, DMODEL, As, Ws, acc);
    else        gemm_core<true, false>(g.A[z], g.W[z], m0, n0, DMODEL, As, Ws, acc);

    const int lane = threadIdx.x & 63;
    const int wv   = threadIdx.x >> 6;
    const int l15  = lane & 15;
    const int quad = lane >> 4;
    const int wm   = wv >> 1;
    const int wn   = wv & 1;
    const float* bias = g.bias[z];
    __bf16* out = g.out[z];
    const float oscale = (z == 0) ? 0.125f : 1.0f;

#pragma unroll
    for (int j = 0; j < 4; ++j) {
        const int col = n0 + wn * 64 + j * 16 + l15;
        const float bcol = (z == 2) ? 0.f : bias[col];
#pragma unroll
        for (int i = 0; i < 4; ++i) {
#pragma unroll
            for (int r = 0; r < 4; ++r) {
                const int row = m0 + wm * 64 + i * 16 + quad * 4 + r;
                size_t idx;
                float v = acc[i][j][r];
                if (z == 2) {
                    const int h = row >> 6, d = row & (DKH - 1);
                    const int b = col >> 11, s = col & (S_LEN - 1);
                    v += bias[row];
                    idx = ((size_t)(b * NHEADS + h) * DKH + d) * S_LEN + s;
                } else {
                    const int b = row >> 11, s = row & (S_LEN - 1);
                    const int h = col >> 6, d = col & (DKH - 1);
                    v = (v + bcol) * oscale;
                    idx = ((size_t)(b * NHEADS + h) * S_LEN + s) * DKH + d;
                }
                out[idx] = (__bf16)v;
            }
        }
    }
}

// ---------------- output projection: fp32 store to d_out ----------------
__global__ __launch_bounds__(256)
void gemm_out(const __bf16* __restrict__ A, const __bf16* __restrict__ W,
              const float* __restrict__ bias, float* __restrict__ out)
{
    __shared__ __align__(16) __bf16 As[128][32];
    __shared__ __align__(16) __bf16 Ws[128][32];

    const int fid = blockIdx.x;          // 256 blocks, XCD-swizzled
    const int x = fid & 7;
    const int t = fid >> 3;
    const int m0 = (x * 4 + (t & 3)) * 128;
    const int n0 = (t >> 2) * 128;

    f32x4 acc[4][4];
#pragma unroll
    for (int i = 0; i < 4; ++i)
#pragma unroll
        for (int j = 0; j < 4; ++j) acc[i][j] = (f32x4){0.f, 0.f, 0.f, 0.f};

    gemm_core<false, false>(A, W, m0, n0, DMODEL, As, Ws, acc);

    const int lane = threadIdx.x & 63;
    const int wv   = threadIdx.x >> 6;
    const int l15  = lane & 15;
    const int quad = lane >> 4;
    const int wm   = wv >> 1;
    const int wn   = wv & 1;

#pragma unroll
    for (int j = 0; j < 4; ++j) {
        const int col = n0 + wn * 64 + j * 16 + l15;
        const float bv = bias[col];
#pragma unroll
        for (int i = 0; i < 4; ++i)
#pragma unroll
            for (int r = 0; r < 4; ++r) {
                const int row = m0 + wm * 64 + i * 16 + quad * 4 + r;
                out[(size_t)row * DMODEL + col] = acc[i][j][r] + bv;
            }
    }
}

// ---------------- flash attention, S^T formulation (unchanged r8) ----------
__global__ __launch_bounds__(256, 2)
void attn_k(const __bf16* __restrict__ Qh, const __bf16* __restrict__ Kh,
            const __bf16* __restrict__ VhT, __bf16* __restrict__ out)
{
    __shared__ __align__(16) __bf16 Ks[128][72];
    __shared__ __align__(16) __bf16 Vs[64][136];

    const int tid  = threadIdx.x;
    const int lane = tid & 63;
    const int wv   = tid >> 6;           // 0..3
    const int l15  = lane & 15;
    const int quad = lane >> 4;

    const int fid = blockIdx.x;
    const int x  = fid & 7;
    const int j  = fid >> 3;
    const int bh = x * 4 + (j & 3);
    const int q0 = (j >> 2) * 128;
    const int b  = bh >> 4;
    const int h  = bh & (NHEADS - 1);

    const __bf16* Q  = Qh  + (size_t)bh * S_LEN * DKH;
    const __bf16* Kp = Kh  + (size_t)bh * S_LEN * DKH;
    const __bf16* Vt = VhT + (size_t)bh * DKH * S_LEN;

    bf16x8 qa[2][2];
#pragma unroll
    for (int u = 0; u < 2; ++u) {
        const int qrow = q0 + wv * 32 + u * 16 + l15;
        qa[u][0] = *(const bf16x8*)(Q + (size_t)qrow * DKH + quad * 8);
        qa[u][1] = *(const bf16x8*)(Q + (size_t)qrow * DKH + quad * 8 + 32);
    }

    const int krow = tid >> 1, kcb = (tid & 1) * 32;
    const int vrow = tid >> 2, vcb = (tid & 3) * 32;
    const __bf16* kst = Kp + (size_t)krow * DKH   + kcb;
    const __bf16* vst = Vt + (size_t)vrow * S_LEN + vcb;

    f32x4 oT[2][4];
#pragma unroll
    for (int u = 0; u < 2; ++u)
#pragma unroll
        for (int jt = 0; jt < 4; ++jt) oT[u][jt] = (f32x4){0.f, 0.f, 0.f, 0.f};
    float lacc[2] = {0.f, 0.f};

    bf16x8 kreg[4], vperm[4];
    {
        bf16x8 vr[4];
#pragma unroll
        for (int p = 0; p < 4; ++p) {
            kreg[p] = *(const bf16x8*)(kst + p * 8);
            vr[p]   = *(const bf16x8*)(vst + p * 8);
        }
#pragma unroll
        for (int p = 0; p < 4; ++p) {
            const int G = (p >> 1), e = (p & 1) * 4;
#pragma unroll
            for (int s = 0; s < 4; ++s) {
                vperm[p][s]     = vr[G][e + s];
                vperm[p][4 + s] = vr[G + 2][e + s];
            }
        }
    }

    for (int kt = 0; kt < S_LEN; kt += 128) {
        __syncthreads();
#pragma unroll
        for (int p = 0; p < 4; ++p) {
            *(bf16x8*)&Ks[krow][kcb + p * 8] = kreg[p];
            *(bf16x8*)&Vs[vrow][vcb + p * 8] = vperm[p];
        }
        __syncthreads();
        if (kt + 128 < S_LEN) {
            bf16x8 vr[4];
#pragma unroll
            for (int p = 0; p < 4; ++p) {
                kreg[p] = *(const bf16x8*)(kst + (size_t)(kt + 128) * DKH + p * 8);
                vr[p]   = *(const bf16x8*)(vst + kt + 128 + p * 8);
            }
#pragma unroll
            for (int p = 0; p < 4; ++p) {
                const int G = (p >> 1), e = (p & 1) * 4;
#pragma unroll
                for (int s = 0; s < 4; ++s) {
                    vperm[p][s]     = vr[G][e + s];
                    vperm[p][4 + s] = vr[G + 2][e + s];
                }
            }
        }

#pragma unroll
        for (int ht = 0; ht < 2; ++ht) {
            float p[2][4][4];
#pragma unroll
            for (int n = 0; n < 4; ++n) {
                bf16x8 kA = *(const bf16x8*)&Ks[ht * 64 + n * 16 + l15][quad * 8];
                bf16x8 kB = *(const bf16x8*)&Ks[ht * 64 + n * 16 + l15][quad * 8 + 32];
#pragma unroll
                for (int u = 0; u < 2; ++u) {
                    f32x4 st = {0.f, 0.f, 0.f, 0.f};
                    st = __builtin_amdgcn_mfma_f32_16x16x32_bf16(kA, qa[u][0], st, 0, 0, 0);
                    st = __builtin_amdgcn_mfma_f32_16x16x32_bf16(kB, qa[u][1], st, 0, 0, 0);
#pragma unroll
                    for (int r = 0; r < 4; ++r) {
                        p[u][n][r] = __expf(st[r]);
                        lacc[u] += p[u][n][r];
                    }
                }
            }

#pragma unroll
            for (int t = 0; t < 2; ++t) {
                bf16x8 pf[2];
#pragma unroll
                for (int u = 0; u < 2; ++u)
#pragma unroll
                    for (int s = 0; s < 4; ++s) {
                        pf[u][s]     = (__bf16)p[u][2 * t][s];
                        pf[u][4 + s] = (__bf16)p[u][2 * t + 1][s];
                    }
#pragma unroll
                for (int jt = 0; jt < 4; ++jt) {
                    bf16x8 vf = *(const bf16x8*)&Vs[jt * 16 + l15][ht * 64 + t * 32 + quad * 8];
#pragma unroll
                    for (int u = 0; u < 2; ++u)
                        oT[u][jt] = __builtin_amdgcn_mfma_f32_16x16x32_bf16(vf, pf[u], oT[u][jt], 0, 0, 0);
                }
            }
        }
    }

#pragma unroll
    for (int u = 0; u < 2; ++u) {
        float l = lacc[u];
        l += __shfl_xor(l, 16);
        l += __shfl_xor(l, 32);
        const float inv = 1.0f / l;
        __bf16* op = out + ((size_t)b * S_LEN + q0 + wv * 32 + u * 16 + l15) * DMODEL + h * DKH;
#pragma unroll
        for (int jt = 0; jt < 4; ++jt) {
            bf16x4 t;
#pragma unroll
            for (int r = 0; r < 4; ++r) t[r] = (__bf16)(oT[u][jt][r] * inv);
            *(bf16x4*)(op + jt * 16 + quad * 4) = t;
        }
    }
}

extern "C" void kernel_launch(void* const* d_in, const int* in_sizes, int n_in,
                              void* d_out, int out_size, void* d_ws, size_t ws_size,
                              hipStream_t stream) {
    const float* Qi = (const float*)d_in[0];
    const float* Ki = (const float*)d_in[1];
    const float* Vi = (const float*)d_in[2];
    const float* Wq = (const float*)d_in[3];
    const float* bq = (const float*)d_in[4];
    const float* Wk = (const float*)d_in[5];
    const float* bk = (const float*)d_in[6];
    const float* Wv = (const float*)d_in[7];
    const float* bv = (const float*)d_in[8];
    const float* Wo = (const float*)d_in[9];
    const float* bo = (const float*)d_in[10];
    float* out = (float*)d_out;

    const size_t NW = (size_t)DMODEL * DMODEL;    // 1 Mi
    const size_t NE = (size_t)NBATCH * S_LEN * DMODEL;  // 4 Mi
    // ws layout: 40 MB total, no aliasing
    __bf16* w_bf    = (__bf16*)d_ws;              // 4 x [D,D]      8 MB
    __bf16* q_ws    = w_bf + 4 * NW;              // [B,H,S,64]     8 MB
    __bf16* k_ws    = q_ws + NE;                  // [B,H,S,64]     8 MB
    __bf16* vT_ws   = k_ws + NE;                  // [B,H,64,S]     8 MB
    __bf16* attn_ws = vT_ws + NE;                 // [B,S,DMODEL]   8 MB
    __bf16* wq_bf = w_bf, *wk_bf = w_bf + NW, *wv_bf = w_bf + 2 * NW, *wo_bf = w_bf + 3 * NW;

    // d1: convert weights only (4 MB)
    cvt_w_k<<<dim3(512, 4), 256, 0, stream>>>(Wq, Wk, Wv, Wo, w_bf);

    // d2: all three projections in ONE dispatch (768 blocks, 3/CU)
    GArgs g;
    g.A[0] = Qi;    g.W[0] = wq_bf; g.bias[0] = bq; g.out[0] = q_ws;
    g.A[1] = Ki;    g.W[1] = wk_bf; g.bias[1] = bk; g.out[1] = k_ws;
    g.A[2] = wv_bf; g.W[2] = Vi;    g.bias[2] = bv; g.out[2] = vT_ws;
    gemm_qkv<<<dim3(768), 256, 0, stream>>>(g);

    // d3: attention
    attn_k<<<dim3(512), 256, 0, stream>>>(q_ws, k_ws, vT_ws, attn_ws);

    // d4: output projection -> fp32 d_out
    gemm_out<<<dim3(256), 256, 0, stream>>>(attn_ws, wo_bf, bo, out);
}

// Round 10
// 249.831 us; speedup vs baseline: 1.0679x; 1.0679x over previous
//
#include <hip/hip_runtime.h>
#include <hip/hip_bf16.h>

#define S_LEN   2048
#define NHEADS  16
#define DKH     64
#define DMODEL  1024
#define NBATCH  2

typedef __bf16 bf16x8 __attribute__((ext_vector_type(8)));
typedef __bf16 bf16x4 __attribute__((ext_vector_type(4)));
typedef float  f32x4  __attribute__((ext_vector_type(4)));

typedef __attribute__((address_space(3))) void       lds_void;
typedef const __attribute__((address_space(1))) void glob_void;

__device__ __forceinline__ void glds16(const void* g, void* l) {
    __builtin_amdgcn_global_load_lds((glob_void*)g, (lds_void*)l, 16, 0, 0);
}

// ---------------- fp32 -> bf16 pre-convert (weights only, 4 MB) -------------
__global__ __launch_bounds__(256)
void cvt_w_k(const float* __restrict__ wq, const float* __restrict__ wk,
             const float* __restrict__ wv, const float* __restrict__ wo,
             __bf16* __restrict__ dst)
{
    const float* srcs[4] = {wq, wk, wv, wo};
    const float* s = srcs[blockIdx.y];
    __bf16* d = dst + (size_t)blockIdx.y * (DMODEL * DMODEL);
    const size_t i = ((size_t)blockIdx.x * 256 + threadIdx.x) * 8;
    f32x4 lo = *(const f32x4*)(s + i);
    f32x4 hi = *(const f32x4*)(s + i + 4);
    bf16x8 r;
#pragma unroll
    for (int k = 0; k < 4; ++k) { r[k] = (__bf16)lo[k]; r[4 + k] = (__bf16)hi[k]; }
    *(bf16x8*)(d + i) = r;
}

// ------------- GEMM core: 64x128 tile, BK=32, occupancy-first -------------
// 256 thr / 4 waves; wave computes 32x64 (8 MFMA/step, acc 2x4).
// AF32: A fp32 via VGPR->cvt->LDS (8 f32/thr); else bf16 via 1 glds16/thr.
// WF32: W fp32 via VGPR->cvt->LDS (16 f32/thr); else bf16 via 2 glds16/thr.
// LDS 12 KB, acc 32 VGPR -> high blocks/CU; drains overlap across blocks.
template<bool AF32, bool WF32>
__device__ __forceinline__ void gemm_core64(
    const void* __restrict__ Ap, const void* __restrict__ Wp,
    int m0, int n0, int K,
    __bf16 (*As)[32], __bf16 (*Ws)[32], f32x4 acc[2][4])
{
    const int tid  = threadIdx.x;
    const int lane = tid & 63;
    const int wv   = tid >> 6;
    const int l15  = lane & 15;
    const int quad = lane >> 4;
    const int wm   = wv >> 1;            // 32-row half
    const int wn   = wv & 1;             // 64-col half
    const int grow = lane >> 2;
    const int gcol = (lane & 3) * 8;

    // bf16 glds maps
    const __bf16* agb = (const __bf16*)Ap + (size_t)(m0 + wv * 16 + grow) * K + gcol;
    const __bf16* wg0 = (const __bf16*)Wp + (size_t)(n0 + wv * 32 + grow) * K + gcol;
    const __bf16* wg1 = (const __bf16*)Wp + (size_t)(n0 + wv * 32 + 16 + grow) * K + gcol;
    void* alb = &As[wv * 16][0];
    void* wl0 = &Ws[wv * 32][0];
    void* wl1 = &Ws[wv * 32 + 16][0];

    // fp32 staging maps
    const int afr = tid >> 2, afc = (tid & 3) * 8;     // A: 64x32, 8 f32/thr
    const int wfr = tid >> 1, wfc = (tid & 1) * 16;    // W: 128x32, 16 f32/thr
    const float* afp = (const float*)Ap + (size_t)(m0 + afr) * K + afc;
    const float* wfp = (const float*)Wp + (size_t)(n0 + wfr) * K + wfc;

    f32x4 apf[2], wpf[4];
    if (AF32) {
        apf[0] = *(const f32x4*)(afp);
        apf[1] = *(const f32x4*)(afp + 4);
    }
    if (WF32) {
#pragma unroll
        for (int t = 0; t < 4; ++t) wpf[t] = *(const f32x4*)(wfp + t * 4);
    }

    for (int k0 = 0;;) {
        __syncthreads();                   // prior frag reads complete
        if (AF32) {
            bf16x8 v;
#pragma unroll
            for (int t = 0; t < 4; ++t) { v[t] = (__bf16)apf[0][t]; v[4 + t] = (__bf16)apf[1][t]; }
            *(bf16x8*)&As[afr][afc] = v;
        } else {
            glds16(agb + k0, alb);
        }
        if (WF32) {
            bf16x8 v0, v1;
#pragma unroll
            for (int t = 0; t < 4; ++t) {
                v0[t] = (__bf16)wpf[0][t]; v0[4 + t] = (__bf16)wpf[1][t];
                v1[t] = (__bf16)wpf[2][t]; v1[4 + t] = (__bf16)wpf[3][t];
            }
            *(bf16x8*)&Ws[wfr][wfc]     = v0;
            *(bf16x8*)&Ws[wfr][wfc + 8] = v1;
        } else {
            glds16(wg0 + k0, wl0);
            glds16(wg1 + k0, wl1);
        }
        __syncthreads();                   // tiles visible
        k0 += 32;
        if (k0 < K) {                      // prefetch next fp32 tiles
            if (AF32) {
                apf[0] = *(const f32x4*)(afp + k0);
                apf[1] = *(const f32x4*)(afp + k0 + 4);
            }
            if (WF32) {
#pragma unroll
                for (int t = 0; t < 4; ++t) wpf[t] = *(const f32x4*)(wfp + k0 + t * 4);
            }
        }

        bf16x8 af[2], wf[4];
#pragma unroll
        for (int i = 0; i < 2; ++i)
            af[i] = *(const bf16x8*)&As[wm * 32 + i * 16 + l15][quad * 8];
#pragma unroll
        for (int j = 0; j < 4; ++j)
            wf[j] = *(const bf16x8*)&Ws[wn * 64 + j * 16 + l15][quad * 8];
#pragma unroll
        for (int i = 0; i < 2; ++i)
#pragma unroll
            for (int j = 0; j < 4; ++j)
                acc[i][j] = __builtin_amdgcn_mfma_f32_16x16x32_bf16(af[i], wf[j], acc[i][j], 0, 0, 0);

        if (k0 >= K) break;
    }
}

// ---------------- single-dispatch QKV projections (1536 blocks) -------------
// z 0: Q = Qi(fp32)@Wq^T (+bq)*0.125 -> [b,h,s,d]
// z 1: K = Ki(fp32)@Wk^T (+bk)       -> [b,h,s,d]
// z 2: vT = Wv(bf16)@Vi(fp32)^T (+bv/row) -> [b,h,d,s] (coalesced)
struct GArgs {
    const void* A[3];
    const void* W[3];
    const float* bias[3];
    __bf16*     out[3];
};

__global__ __launch_bounds__(256, 5)
void gemm_qkv(GArgs g)
{
    __shared__ __align__(16) __bf16 As[64][32];
    __shared__ __align__(16) __bf16 Ws[128][32];

    const int fid = blockIdx.x;
    const int z   = fid >> 9;            // 0..2
    const int l   = fid & 511;
    const int x   = l & 7;               // XCD (heuristic: XCD = blockIdx % 8)
    const int t   = l >> 3;              // 0..63
    int m0, n0;
    if (z == 2) { m0 = (t & 15) * 64;          n0 = (x * 4 + (t >> 4)) * 128; }  // 16m(d) x 32n(s)
    else        { m0 = (x * 8 + (t & 7)) * 64; n0 = (t >> 3) * 128; }            // 64m(s) x 8n(d)

    f32x4 acc[2][4];
#pragma unroll
    for (int i = 0; i < 2; ++i)
#pragma unroll
        for (int j = 0; j < 4; ++j) acc[i][j] = (f32x4){0.f, 0.f, 0.f, 0.f};

    if (z == 2) gemm_core64<false, true>(g.A[2], g.W[2], m0, n0, DMODEL, As, Ws, acc);
    else        gemm_core64<true, false>(g.A[z], g.W[z], m0, n0, DMODEL, As, Ws, acc);

    const int lane = threadIdx.x & 63;
    const int wv   = threadIdx.x >> 6;
    const int l15  = lane & 15;
    const int quad = lane >> 4;
    const int wm   = wv >> 1;
    const int wn   = wv & 1;
    const float* bias = g.bias[z];
    __bf16* out = g.out[z];
    const float oscale = (z == 0) ? 0.125f : 1.0f;

#pragma unroll
    for (int j = 0; j < 4; ++j) {
        const int col = n0 + wn * 64 + j * 16 + l15;
        const float bcol = (z == 2) ? 0.f : bias[col];
#pragma unroll
        for (int i = 0; i < 2; ++i) {
#pragma unroll
            for (int r = 0; r < 4; ++r) {
                const int row = m0 + wm * 32 + i * 16 + quad * 4 + r;
                size_t idx;
                float v = acc[i][j][r];
                if (z == 2) {
                    const int h = row >> 6, d = row & (DKH - 1);
                    const int b = col >> 11, s = col & (S_LEN - 1);
                    v += bias[row];
                    idx = ((size_t)(b * NHEADS + h) * DKH + d) * S_LEN + s;
                } else {
                    const int b = row >> 11, s = row & (S_LEN - 1);
                    const int h = col >> 6, d = col & (DKH - 1);
                    v = (v + bcol) * oscale;
                    idx = ((size_t)(b * NHEADS + h) * S_LEN + s) * DKH + d;
                }
                out[idx] = (__bf16)v;
            }
        }
    }
}

// ---------------- output projection: 512 blocks, fp32 store ----------------
__global__ __launch_bounds__(256, 5)
void gemm_out(const __bf16* __restrict__ A, const __bf16* __restrict__ W,
              const float* __restrict__ bias, float* __restrict__ out)
{
    __shared__ __align__(16) __bf16 As[64][32];
    __shared__ __align__(16) __bf16 Ws[128][32];

    const int fid = blockIdx.x;
    const int x = fid & 7;
    const int t = fid >> 3;              // 0..63
    const int m0 = (x * 8 + (t & 7)) * 64;
    const int n0 = (t >> 3) * 128;

    f32x4 acc[2][4];
#pragma unroll
    for (int i = 0; i < 2; ++i)
#pragma unroll
        for (int j = 0; j < 4; ++j) acc[i][j] = (f32x4){0.f, 0.f, 0.f, 0.f};

    gemm_core64<false, false>(A, W, m0, n0, DMODEL, As, Ws, acc);

    const int lane = threadIdx.x & 63;
    const int wv   = threadIdx.x >> 6;
    const int l15  = lane & 15;
    const int quad = lane >> 4;
    const int wm   = wv >> 1;
    const int wn   = wv & 1;

#pragma unroll
    for (int j = 0; j < 4; ++j) {
        const int col = n0 + wn * 64 + j * 16 + l15;
        const float bv = bias[col];
#pragma unroll
        for (int i = 0; i < 2; ++i)
#pragma unroll
            for (int r = 0; r < 4; ++r) {
                const int row = m0 + wm * 32 + i * 16 + quad * 4 + r;
                out[(size_t)row * DMODEL + col] = acc[i][j][r] + bv;
            }
    }
}

// ---------------- flash attention, S^T formulation (r8 version) ------------
__global__ __launch_bounds__(256, 2)
void attn_k(const __bf16* __restrict__ Qh, const __bf16* __restrict__ Kh,
            const __bf16* __restrict__ VhT, __bf16* __restrict__ out)
{
    __shared__ __align__(16) __bf16 Ks[128][72];
    __shared__ __align__(16) __bf16 Vs[64][136];

    const int tid  = threadIdx.x;
    const int lane = tid & 63;
    const int wv   = tid >> 6;           // 0..3
    const int l15  = lane & 15;
    const int quad = lane >> 4;

    const int fid = blockIdx.x;
    const int x  = fid & 7;
    const int j  = fid >> 3;
    const int bh = x * 4 + (j & 3);
    const int q0 = (j >> 2) * 128;
    const int b  = bh >> 4;
    const int h  = bh & (NHEADS - 1);

    const __bf16* Q  = Qh  + (size_t)bh * S_LEN * DKH;
    const __bf16* Kp = Kh  + (size_t)bh * S_LEN * DKH;
    const __bf16* Vt = VhT + (size_t)bh * DKH * S_LEN;

    bf16x8 qa[2][2];
#pragma unroll
    for (int u = 0; u < 2; ++u) {
        const int qrow = q0 + wv * 32 + u * 16 + l15;
        qa[u][0] = *(const bf16x8*)(Q + (size_t)qrow * DKH + quad * 8);
        qa[u][1] = *(const bf16x8*)(Q + (size_t)qrow * DKH + quad * 8 + 32);
    }

    const int krow = tid >> 1, kcb = (tid & 1) * 32;
    const int vrow = tid >> 2, vcb = (tid & 3) * 32;
    const __bf16* kst = Kp + (size_t)krow * DKH   + kcb;
    const __bf16* vst = Vt + (size_t)vrow * S_LEN + vcb;

    f32x4 oT[2][4];
#pragma unroll
    for (int u = 0; u < 2; ++u)
#pragma unroll
        for (int jt = 0; jt < 4; ++jt) oT[u][jt] = (f32x4){0.f, 0.f, 0.f, 0.f};
    float lacc[2] = {0.f, 0.f};

    bf16x8 kreg[4], vperm[4];
    {
        bf16x8 vr[4];
#pragma unroll
        for (int p = 0; p < 4; ++p) {
            kreg[p] = *(const bf16x8*)(kst + p * 8);
            vr[p]   = *(const bf16x8*)(vst + p * 8);
        }
#pragma unroll
        for (int p = 0; p < 4; ++p) {
            const int G = (p >> 1), e = (p & 1) * 4;
#pragma unroll
            for (int s = 0; s < 4; ++s) {
                vperm[p][s]     = vr[G][e + s];
                vperm[p][4 + s] = vr[G + 2][e + s];
            }
        }
    }

    for (int kt = 0; kt < S_LEN; kt += 128) {
        __syncthreads();
#pragma unroll
        for (int p = 0; p < 4; ++p) {
            *(bf16x8*)&Ks[krow][kcb + p * 8] = kreg[p];
            *(bf16x8*)&Vs[vrow][vcb + p * 8] = vperm[p];
        }
        __syncthreads();
        if (kt + 128 < S_LEN) {
            bf16x8 vr[4];
#pragma unroll
            for (int p = 0; p < 4; ++p) {
                kreg[p] = *(const bf16x8*)(kst + (size_t)(kt + 128) * DKH + p * 8);
                vr[p]   = *(const bf16x8*)(vst + kt + 128 + p * 8);
            }
#pragma unroll
            for (int p = 0; p < 4; ++p) {
                const int G = (p >> 1), e = (p & 1) * 4;
#pragma unroll
                for (int s = 0; s < 4; ++s) {
                    vperm[p][s]     = vr[G][e + s];
                    vperm[p][4 + s] = vr[G + 2][e + s];
                }
            }
        }

#pragma unroll
        for (int ht = 0; ht < 2; ++ht) {
            float p[2][4][4];
#pragma unroll
            for (int n = 0; n < 4; ++n) {
                bf16x8 kA = *(const bf16x8*)&Ks[ht * 64 + n * 16 + l15][quad * 8];
                bf16x8 kB = *(const bf16x8*)&Ks[ht * 64 + n * 16 + l15][quad * 8 + 32];
#pragma unroll
                for (int u = 0; u < 2; ++u) {
                    f32x4 st = {0.f, 0.f, 0.f, 0.f};
                    st = __builtin_amdgcn_mfma_f32_16x16x32_bf16(kA, qa[u][0], st, 0, 0, 0);
                    st = __builtin_amdgcn_mfma_f32_16x16x32_bf16(kB, qa[u][1], st, 0, 0, 0);
#pragma unroll
                    for (int r = 0; r < 4; ++r) {
                        p[u][n][r] = __expf(st[r]);
                        lacc[u] += p[u][n][r];
                    }
                }
            }

#pragma unroll
            for (int t = 0; t < 2; ++t) {
                bf16x8 pf[2];
#pragma unroll
                for (int u = 0; u < 2; ++u)
#pragma unroll
                    for (int s = 0; s < 4; ++s) {
                        pf[u][s]     = (__bf16)p[u][2 * t][s];
                        pf[u][4 + s] = (__bf16)p[u][2 * t + 1][s];
                    }
#pragma unroll
                for (int jt = 0; jt < 4; ++jt) {
                    bf16x8 vf = *(const bf16x8*)&Vs[jt * 16 + l15][ht * 64 + t * 32 + quad * 8];
#pragma unroll
                    for (int u = 0; u < 2; ++u)
                        oT[u][jt] = __builtin_amdgcn_mfma_f32_16x16x32_bf16(vf, pf[u], oT[u][jt], 0, 0, 0);
                }
            }
        }
    }

#pragma unroll
    for (int u = 0; u < 2; ++u) {
        float l = lacc[u];
        l += __shfl_xor(l, 16);
        l += __shfl_xor(l, 32);
        const float inv = 1.0f / l;
        __bf16* op = out + ((size_t)b * S_LEN + q0 + wv * 32 + u * 16 + l15) * DMODEL + h * DKH;
#pragma unroll
        for (int jt = 0; jt < 4; ++jt) {
            bf16x4 t;
#pragma unroll
            for (int r = 0; r < 4; ++r) t[r] = (__bf16)(oT[u][jt][r] * inv);
            *(bf16x4*)(op + jt * 16 + quad * 4) = t;
        }
    }
}

extern "C" void kernel_launch(void* const* d_in, const int* in_sizes, int n_in,
                              void* d_out, int out_size, void* d_ws, size_t ws_size,
                              hipStream_t stream) {
    const float* Qi = (const float*)d_in[0];
    const float* Ki = (const float*)d_in[1];
    const float* Vi = (const float*)d_in[2];
    const float* Wq = (const float*)d_in[3];
    const float* bq = (const float*)d_in[4];
    const float* Wk = (const float*)d_in[5];
    const float* bk = (const float*)d_in[6];
    const float* Wv = (const float*)d_in[7];
    const float* bv = (const float*)d_in[8];
    const float* Wo = (const float*)d_in[9];
    const float* bo = (const float*)d_in[10];
    float* out = (float*)d_out;

    const size_t NW = (size_t)DMODEL * DMODEL;          // 1 Mi
    const size_t NE = (size_t)NBATCH * S_LEN * DMODEL;  // 4 Mi
    __bf16* w_bf    = (__bf16*)d_ws;              // 4 x [D,D]      8 MB
    __bf16* q_ws    = w_bf + 4 * NW;              // [B,H,S,64]     8 MB
    __bf16* k_ws    = q_ws + NE;                  // [B,H,S,64]     8 MB
    __bf16* vT_ws   = k_ws + NE;                  // [B,H,64,S]     8 MB
    __bf16* attn_ws = vT_ws + NE;                 // [B,S,DMODEL]   8 MB
    __bf16* wq_bf = w_bf, *wk_bf = w_bf + NW, *wv_bf = w_bf + 2 * NW, *wo_bf = w_bf + 3 * NW;

    // d1: convert weights only (4 MB)
    cvt_w_k<<<dim3(512, 4), 256, 0, stream>>>(Wq, Wk, Wv, Wo, w_bf);

    // d2: all three projections, 1536 blocks = 6 blocks/CU
    GArgs g;
    g.A[0] = Qi;    g.W[0] = wq_bf; g.bias[0] = bq; g.out[0] = q_ws;
    g.A[1] = Ki;    g.W[1] = wk_bf; g.bias[1] = bk; g.out[1] = k_ws;
    g.A[2] = wv_bf; g.W[2] = Vi;    g.bias[2] = bv; g.out[2] = vT_ws;
    gemm_qkv<<<dim3(1536), 256, 0, stream>>>(g);

    // d3: attention
    attn_k<<<dim3(512), 256, 0, stream>>>(q_ws, k_ws, vT_ws, attn_ws);

    // d4: output projection -> fp32 d_out (512 blocks = 2/CU)
    gemm_out<<<dim3(512), 256, 0, stream>>>(attn_ws, wo_bf, bo, out);
}